// Round 3
// baseline (19758.730 us; speedup 1.0000x reference)
//
#include <hip/hip_runtime.h>

#define TT 200
#define BB 128
#define CC 171
#define HH 1024
#define XPAD 192
#define FOURH 4096

typedef __attribute__((ext_vector_type(8))) short short8;
typedef __attribute__((ext_vector_type(4))) float f32x4;

__device__ __forceinline__ unsigned short f2bf(float f) {
  unsigned int u = __float_as_uint(f);
  u += 0x7fff + ((u >> 16) & 1);   // RNE
  return (unsigned short)(u >> 16);
}
__device__ __forceinline__ float sigmoidf_(float x) { return 1.f / (1.f + __expf(-x)); }

__device__ __forceinline__ void gload_lds16(const void* g, void* l) {
  __builtin_amdgcn_global_load_lds(
      (const __attribute__((address_space(1))) void*)g,
      (__attribute__((address_space(3))) void*)l, 16, 0, 0);
}

// ---------------- two-level grid barrier (epoch-based) ----------------
// bar layout (ints): grp cnt g at [g*32], grp gen g at [(8+g)*32],
// master cnt at [512], master gen at [544]. All zeroed by init_state each launch.
__device__ __forceinline__ void gridbar(int* bar, int wg, int tid, int epoch) {
  __syncthreads();                      // all waves' stores drained to L2 (vmcnt0 at barrier)
  if (tid == 0) {
    __threadfence();                    // release: writeback L2 so other XCDs can see
    int g = wg & 7;
    int old = __hip_atomic_fetch_add(&bar[g * 32], 1, __ATOMIC_ACQ_REL, __HIP_MEMORY_SCOPE_AGENT);
    if (old == 31) {
      int mold = __hip_atomic_fetch_add(&bar[512], 1, __ATOMIC_ACQ_REL, __HIP_MEMORY_SCOPE_AGENT);
      if (mold == 7) {
        __hip_atomic_store(&bar[512], 0, __ATOMIC_RELAXED, __HIP_MEMORY_SCOPE_AGENT);
        __hip_atomic_store(&bar[544], epoch, __ATOMIC_RELEASE, __HIP_MEMORY_SCOPE_AGENT);
      } else {
        while (__hip_atomic_load(&bar[544], __ATOMIC_RELAXED, __HIP_MEMORY_SCOPE_AGENT) < epoch)
          __builtin_amdgcn_s_sleep(1);
      }
      __hip_atomic_store(&bar[g * 32], 0, __ATOMIC_RELAXED, __HIP_MEMORY_SCOPE_AGENT);
      __hip_atomic_store(&bar[(8 + g) * 32], epoch, __ATOMIC_RELEASE, __HIP_MEMORY_SCOPE_AGENT);
    } else {
      while (__hip_atomic_load(&bar[(8 + g) * 32], __ATOMIC_RELAXED, __HIP_MEMORY_SCOPE_AGENT) < epoch)
        __builtin_amdgcn_s_sleep(1);
    }
    __threadfence();                    // acquire: invalidate caches before reading others' data
  }
  __syncthreads();
}

// ---------------- fused GEMM + LSTM cell phase (device function) ----------------
// 16 waves = 4 K-groups x 4 gate-waves; tile M32 x N64 (permuted); K-split partials
// reduced through LDS, then cell update. LDS: 4 groups * 2 bufs * 12KB = 96KB staging.
__device__ __forceinline__ void lstm_phase(
    const unsigned short* __restrict__ A1, int sA1, int nkt1,
    const unsigned short* __restrict__ A2, int sA2,
    const unsigned short* __restrict__ W, int sW, int nktTot,
    const float* __restrict__ bias,
    float* __restrict__ Cst, unsigned short* __restrict__ Hout,
    char* smem, int m0, int n0, int ntile, int tid)
{
  const int wave = tid >> 6, lane = tid & 63;
  const int grp = wave >> 2, gw = wave & 3;
  const int lrow = lane >> 3, lj = lane & 7;
  const int fl = lane & 15, fh = lane >> 4;

  const int base_cnt = nktTot >> 2;
  const int rem = nktTot & 3;
  const int kt0 = grp * base_cnt + min(grp, rem);
  const int ktn = base_cnt + (grp < rem ? 1 : 0);
  const int maxkt = base_cnt + (rem ? 1 : 0);

  char* gbase = smem + grp * 24576;

  auto stage = [&](int kt, int buf) {
    char* b = gbase + buf * 12288;
    {   // A chunk: rows gw*8 .. gw*8+7 of the 32-row tile
      int row = gw * 8 + lrow;
      const unsigned short* src; int col;
      if (kt < nkt1) { src = A1 + (size_t)(m0 + row) * sA1; col = kt * 64; }
      else           { src = A2 + (size_t)(m0 + row) * sA2; col = (kt - nkt1) * 64; }
      gload_lds16(src + col + ((lj ^ (row & 7)) << 3), b + gw * 1024);
    }
    int k0 = kt * 64;
#pragma unroll
    for (int i = 0; i < 2; ++i) {   // B chunks: rows gw*16+i*8 .. +7 of 64-row tile
      int brow = gw * 16 + i * 8 + lrow;
      gload_lds16(W + (size_t)(n0 + brow) * sW + k0 + ((lj ^ (brow & 7)) << 3),
                  b + 4096 + (gw * 16 + i * 8) * 128);
    }
  };

  f32x4 acc0 = {0.f, 0.f, 0.f, 0.f}, acc1 = {0.f, 0.f, 0.f, 0.f};
  stage(kt0, 0);
  __syncthreads();
  for (int i = 0; i < maxkt; ++i) {
    int cur = i & 1;
    if (i + 1 < ktn) stage(kt0 + i + 1, cur ^ 1);
    if (i < ktn) {
      char* Ab = gbase + cur * 12288;
      char* Bb = Ab + 4096;
#pragma unroll
      for (int kk = 0; kk < 2; ++kk) {
        int colb = kk * 64 + fh * 16;
        int ar0 = fl, ar1 = 16 + fl;
        short8 a0 = *(const short8*)(Ab + ar0 * 128 + (colb ^ ((ar0 & 7) << 4)));
        short8 a1 = *(const short8*)(Ab + ar1 * 128 + (colb ^ ((ar1 & 7) << 4)));
        int br = gw * 16 + fl;
        short8 b0 = *(const short8*)(Bb + br * 128 + (colb ^ ((br & 7) << 4)));
        acc0 = __builtin_amdgcn_mfma_f32_16x16x32_bf16(a0, b0, acc0, 0, 0, 0);
        acc1 = __builtin_amdgcn_mfma_f32_16x16x32_bf16(a1, b0, acc1, 0, 0, 0);
      }
    }
    __syncthreads();
  }

  // partial exchange: ex[grp][gate][row 0..31][unit 0..15] fp32 = 32 KB (reuses staging LDS)
  float* ex = (float*)smem;
#pragma unroll
  for (int r = 0; r < 4; ++r) {
    ex[((grp * 4 + gw) * 32 + (fh * 4 + r)) * 16 + fl] = acc0[r];
    ex[((grp * 4 + gw) * 32 + 16 + (fh * 4 + r)) * 16 + fl] = acc1[r];
  }
  __syncthreads();
  if (tid < 512) {
    int row = tid >> 4, uu = tid & 15;
    float g4[4];
#pragma unroll
    for (int gg = 0; gg < 4; ++gg) {
      float s = ex[((0 + gg) * 32 + row) * 16 + uu] + ex[((4 + gg) * 32 + row) * 16 + uu]
              + ex[((8 + gg) * 32 + row) * 16 + uu] + ex[((12 + gg) * 32 + row) * 16 + uu];
      g4[gg] = s + bias[n0 + gg * 16 + uu];
    }
    int batch = m0 + row;
    int unit = ntile * 16 + uu;
    size_t ci = (size_t)batch * HH + unit;
    float c = Cst[ci];
    float cn = sigmoidf_(g4[1]) * c + sigmoidf_(g4[0]) * tanhf(g4[2]);
    Cst[ci] = cn;
    Hout[ci] = f2bf(sigmoidf_(g4[3]) * tanhf(cn));
  }
}

// ---------------- decoder phase: 44 active WGs, 16-way K-split, wave-private staging ----
__device__ __forceinline__ void dec_phase(
    const unsigned short* __restrict__ H3in, const unsigned short* __restrict__ Wd,
    const float* __restrict__ bd, float* __restrict__ out,
    const float* __restrict__ seq, unsigned short* __restrict__ X,
    int gt, int cond, int t, char* smem, int wg, int tid)
{
  if (wg < 44) {
    const int wave = tid >> 6, lane = tid & 63;
    const int lrow = lane >> 3, lj = lane & 7;
    const int fl = lane & 15, fh = lane >> 4;
    const int ntile = wg % 11, mtile = wg / 11;
    const int m0 = mtile * 32, n0 = ntile * 16;
    char* b = smem + wave * 6144;
    int k0 = wave * 64;
#pragma unroll
    for (int i = 0; i < 4; ++i) {   // A 32x64 private
      int row = i * 8 + lrow;
      gload_lds16(H3in + (size_t)(m0 + row) * HH + k0 + ((lj ^ (row & 7)) << 3), b + i * 1024);
    }
#pragma unroll
    for (int i = 0; i < 2; ++i) {   // B 16x64 private
      int row = i * 8 + lrow;
      gload_lds16(Wd + (size_t)(n0 + row) * HH + k0 + ((lj ^ (row & 7)) << 3), b + 4096 + i * 1024);
    }
    asm volatile("s_waitcnt vmcnt(0)" ::: "memory");
    f32x4 acc0 = {0.f, 0.f, 0.f, 0.f}, acc1 = {0.f, 0.f, 0.f, 0.f};
#pragma unroll
    for (int kk = 0; kk < 2; ++kk) {
      int colb = kk * 64 + fh * 16;
      int ar0 = fl, ar1 = 16 + fl;
      short8 a0 = *(const short8*)(b + ar0 * 128 + (colb ^ ((ar0 & 7) << 4)));
      short8 a1 = *(const short8*)(b + ar1 * 128 + (colb ^ ((ar1 & 7) << 4)));
      short8 b0 = *(const short8*)(b + 4096 + fl * 128 + (colb ^ ((fl & 7) << 4)));
      acc0 = __builtin_amdgcn_mfma_f32_16x16x32_bf16(a0, b0, acc0, 0, 0, 0);
      acc1 = __builtin_amdgcn_mfma_f32_16x16x32_bf16(a1, b0, acc1, 0, 0, 0);
    }
    float* pex = (float*)(smem + 98304);   // [wave][32 rows][16 units]
#pragma unroll
    for (int r = 0; r < 4; ++r) {
      pex[(wave * 32 + fh * 4 + r) * 16 + fl] = acc0[r];
      pex[(wave * 32 + 16 + fh * 4 + r) * 16 + fl] = acc1[r];
    }
    __syncthreads();
    if (tid < 512) {
      int row = tid >> 4, uu = tid & 15;
      int c = n0 + uu;
      if (c < CC) {
        float s = 0.f;
#pragma unroll
        for (int v = 0; v < 16; ++v) s += pex[(v * 32 + row) * 16 + uu];
        float val = s + bd[c];
        int batch = m0 + row;
        out[(size_t)batch * (TT * CC) + (size_t)t * CC + c] = val;
        if (t + 1 < TT) {
          int per = gt + cond;
          bool ug = (per > 0) ? (((t + 1) % per) < gt) : false;
          float xv = ug ? seq[(size_t)batch * (TT * CC) + (size_t)(t + 1) * CC + c] : val;
          X[batch * XPAD + c] = f2bf(xv);
        }
      }
    }
  }
}

// ---------------- persistent megakernel ----------------
__global__ __launch_bounds__(1024) void persistent_lstm(
    const unsigned short* __restrict__ W1, const unsigned short* __restrict__ W2,
    const unsigned short* __restrict__ W3, const unsigned short* __restrict__ Wd,
    const float* __restrict__ B1, const float* __restrict__ B2,
    const float* __restrict__ B3, const float* __restrict__ Bd,
    unsigned short* __restrict__ Hb, float* __restrict__ Cb, unsigned short* __restrict__ X,
    const float* __restrict__ seq, float* __restrict__ out,
    const int* __restrict__ gtp, const int* __restrict__ condp, int* __restrict__ bar)
{
  __shared__ char smem[131072];
  const int wg = blockIdx.x, tid = threadIdx.x;
  // XCD-aware tile map: the 4 WGs sharing a B-panel land on the same XCD (wg%8 = XCD)
  const int xg = wg & 7, sl = wg >> 3;
  const int ntile = xg * 8 + (sl >> 2);
  const int m0 = (sl & 3) * 32;
  const int n0 = ntile * 64;
  const int gt = *gtp, cond = *condp;

  unsigned short* H1[2] = { Hb + 0 * BB * HH, Hb + 1 * BB * HH };
  unsigned short* H2[2] = { Hb + 2 * BB * HH, Hb + 3 * BB * HH };
  unsigned short* H3[2] = { Hb + 4 * BB * HH, Hb + 5 * BB * HH };
  float* C1 = Cb;
  float* C2 = Cb + BB * HH;
  float* C3 = Cb + 2 * BB * HH;

  int epoch = 0;
  for (int t = 0; t < TT; ++t) {
    int p = t & 1;
    lstm_phase(X, XPAD, 3, H1[p], HH, W1, 1216, 19, B1, C1, H1[1 - p], smem, m0, n0, ntile, tid);
    gridbar(bar, wg, tid, ++epoch);
    lstm_phase(H1[1 - p], HH, 16, H2[p], HH, W2, 2048, 32, B2, C2, H2[1 - p], smem, m0, n0, ntile, tid);
    gridbar(bar, wg, tid, ++epoch);
    lstm_phase(H2[1 - p], HH, 16, H3[p], HH, W3, 2048, 32, B3, C3, H3[1 - p], smem, m0, n0, ntile, tid);
    gridbar(bar, wg, tid, ++epoch);
    dec_phase(H3[1 - p], Wd, Bd, out, seq, X, gt, cond, t, smem, wg, tid);
    gridbar(bar, wg, tid, ++epoch);
  }
}

// ---------------- conversion / init kernels ----------------
__device__ __forceinline__ int perm_orig_row(int np) {
  return ((np >> 4) & 3) * HH + ((np >> 6) << 4) + (np & 15);
}

__global__ void conv_w1(const float* __restrict__ Wih, const float* __restrict__ Whh,
                        unsigned short* __restrict__ dst) {
  int k = blockIdx.x * 256 + threadIdx.x;
  int np = blockIdx.y;
  if (k >= 1216) return;
  int n = perm_orig_row(np);
  float v;
  if (k < XPAD) v = (k < CC) ? Wih[(size_t)n * CC + k] : 0.f;
  else          v = Whh[(size_t)n * HH + (k - XPAD)];
  dst[(size_t)np * 1216 + k] = f2bf(v);
}

__global__ void conv_w23(const float* __restrict__ Wih, const float* __restrict__ Whh,
                         unsigned short* __restrict__ dst) {
  int k = blockIdx.x * 256 + threadIdx.x;
  int np = blockIdx.y;
  int n = perm_orig_row(np);
  float v = (k < HH) ? Wih[(size_t)n * HH + k] : Whh[(size_t)n * HH + (k - HH)];
  dst[(size_t)np * 2048 + k] = f2bf(v);
}

__global__ void conv_wd(const float* __restrict__ Wsrc, unsigned short* __restrict__ dst) {
  int k = blockIdx.x * 256 + threadIdx.x;
  int row = blockIdx.y;
  float v = (row < CC) ? Wsrc[(size_t)row * HH + k] : 0.f;
  dst[(size_t)row * HH + k] = f2bf(v);
}

__global__ void conv_bias(const float* bi1, const float* bh1, const float* bi2, const float* bh2,
                          const float* bi3, const float* bh3, const float* bdec,
                          float* o1, float* o2, float* o3, float* od) {
  int idx = blockIdx.x * 256 + threadIdx.x;
  if (idx < 3 * FOURH) {
    int l = idx >> 12; int np = idx & 4095;
    int n = perm_orig_row(np);
    const float* bi = (l == 0) ? bi1 : ((l == 1) ? bi2 : bi3);
    const float* bh = (l == 0) ? bh1 : ((l == 1) ? bh2 : bh3);
    float* o = (l == 0) ? o1 : ((l == 1) ? o2 : o3);
    o[np] = bi[n] + bh[n];
  } else {
    int c2 = idx - 3 * FOURH;
    if (c2 < 176) od[c2] = (c2 < CC) ? bdec[c2] : 0.f;
  }
}

__global__ void init_state(unsigned short* __restrict__ Hall, float* __restrict__ Call,
                           unsigned short* __restrict__ X, const float* __restrict__ seq,
                           const int* __restrict__ gtp, int* __restrict__ bar) {
  int idx = blockIdx.x * blockDim.x + threadIdx.x;
  if (idx < 3 * 2 * BB * HH) Hall[idx] = 0;
  if (idx < 3 * BB * HH) Call[idx] = 0.f;
  if (idx < BB * XPAD) {
    int b = idx / XPAD, cc = idx % XPAD;
    float v = 0.f;
    if (cc < CC && (*gtp) > 0) v = seq[(size_t)b * TT * CC + cc];
    X[idx] = f2bf(v);
  }
  if (idx < 1024) bar[idx] = 0;
}

extern "C" void kernel_launch(void* const* d_in, const int* in_sizes, int n_in,
                              void* d_out, int out_size, void* d_ws, size_t ws_size,
                              hipStream_t stream)
{
  const float* seq   = (const float*)d_in[0];
  const float* W_ih1 = (const float*)d_in[1];
  const float* W_hh1 = (const float*)d_in[2];
  const float* b_ih1 = (const float*)d_in[3];
  const float* b_hh1 = (const float*)d_in[4];
  const float* W_ih2 = (const float*)d_in[5];
  const float* W_hh2 = (const float*)d_in[6];
  const float* b_ih2 = (const float*)d_in[7];
  const float* b_hh2 = (const float*)d_in[8];
  const float* W_ih3 = (const float*)d_in[9];
  const float* W_hh3 = (const float*)d_in[10];
  const float* b_ih3 = (const float*)d_in[11];
  const float* b_hh3 = (const float*)d_in[12];
  const float* W_dec = (const float*)d_in[13];
  const float* b_dec = (const float*)d_in[14];
  const int* condp   = (const int*)d_in[15];
  const int* gtp     = (const int*)d_in[16];
  float* out = (float*)d_out;
  char* ws = (char*)d_ws;

  if (ws_size < 47272960) return;

  unsigned short* W1 = (unsigned short*)(ws + 0);
  unsigned short* W2 = (unsigned short*)(ws + 9961472);
  unsigned short* W3 = (unsigned short*)(ws + 26738688);
  unsigned short* Wd = (unsigned short*)(ws + 43515904);
  float* B1 = (float*)(ws + 43876352);
  float* B2 = (float*)(ws + 43941888);
  float* B3 = (float*)(ws + 44007424);
  float* Bd = (float*)(ws + 44072960);
  unsigned short* Hbase = (unsigned short*)(ws + 44073984);
  float* Cbase = (float*)(ws + 45646848);
  unsigned short* X = (unsigned short*)(ws + 47219712);
  int* bar = (int*)(ws + 47268864);

  conv_w1 <<<dim3(5, 4096), 256, 0, stream>>>(W_ih1, W_hh1, W1);
  conv_w23<<<dim3(8, 4096), 256, 0, stream>>>(W_ih2, W_hh2, W2);
  conv_w23<<<dim3(8, 4096), 256, 0, stream>>>(W_ih3, W_hh3, W3);
  conv_wd <<<dim3(4, 176),  256, 0, stream>>>(W_dec, Wd);
  conv_bias<<<dim3(49), 256, 0, stream>>>(b_ih1, b_hh1, b_ih2, b_hh2, b_ih3, b_hh3, b_dec,
                                          B1, B2, B3, Bd);
  init_state<<<dim3(3072), 256, 0, stream>>>(Hbase, Cbase, X, seq, gtp, bar);

  persistent_lstm<<<dim3(256), dim3(1024), 0, stream>>>(
      W1, W2, W3, Wd, B1, B2, B3, Bd, Hbase, Cbase, X, seq, out, gtp, condp, bar);
}

// Round 5
// 7684.662 us; speedup vs baseline: 2.5712x; 2.5712x over previous
//
#include <hip/hip_runtime.h>

#define TT 200
#define BB 128
#define CC 171
#define HH 1024
#define XPAD 192
#define FOURH 4096

typedef __attribute__((ext_vector_type(8))) short short8;
typedef __attribute__((ext_vector_type(4))) float f32x4;

__device__ __forceinline__ unsigned short f2bf(float f) {
  unsigned int u = __float_as_uint(f);
  u += 0x7fff + ((u >> 16) & 1);   // RNE
  return (unsigned short)(u >> 16);
}
__device__ __forceinline__ float sigmoidf_(float x) { return 1.f / (1.f + __expf(-x)); }

// coherent (cross-XCD) 16B load: bypass L1+L2, served at Infinity Cache
__device__ __forceinline__ int4 ld_coh16(const void* p) {
  int4 r;
  asm volatile("global_load_dwordx4 %0, %1, off sc0 sc1" : "=v"(r) : "v"(p));
  return r;
}
// coherent 2B store (write-through to IF$)
__device__ __forceinline__ void st_coh2(void* p, unsigned int v) {
  asm volatile("global_store_short %0, %1, off sc0 sc1" :: "v"(p), "v"(v) : "memory");
}
// inline-asm memory ops are NOT tracked by the compiler's waitcnt insertion —
// every consumer of ld_coh16 results / every barrier after st_coh2 needs this:
__device__ __forceinline__ void drain_vm() {
  asm volatile("s_waitcnt vmcnt(0)" ::: "memory");
}

// ---------------- two-level grid barrier, NO cache maintenance ----------------
__device__ __forceinline__ void gridbar(int* bar, int wg, int tid, int epoch) {
  drain_vm();        // sc-stores (inline asm, untracked) must be IF$-visible before arrival
  __syncthreads();
  if (tid == 0) {
    int g = wg & 7;
    if (__hip_atomic_fetch_add(&bar[g * 32], 1, __ATOMIC_RELAXED, __HIP_MEMORY_SCOPE_AGENT) == 31) {
      if (__hip_atomic_fetch_add(&bar[512], 1, __ATOMIC_RELAXED, __HIP_MEMORY_SCOPE_AGENT) == 7) {
        __hip_atomic_store(&bar[512], 0, __ATOMIC_RELAXED, __HIP_MEMORY_SCOPE_AGENT);
        __hip_atomic_store(&bar[544], epoch, __ATOMIC_RELAXED, __HIP_MEMORY_SCOPE_AGENT);
      } else {
        while (__hip_atomic_load(&bar[544], __ATOMIC_RELAXED, __HIP_MEMORY_SCOPE_AGENT) < epoch)
          __builtin_amdgcn_s_sleep(1);
      }
      __hip_atomic_store(&bar[g * 32], 0, __ATOMIC_RELAXED, __HIP_MEMORY_SCOPE_AGENT);
      __hip_atomic_store(&bar[(8 + g) * 32], epoch, __ATOMIC_RELAXED, __HIP_MEMORY_SCOPE_AGENT);
    } else {
      while (__hip_atomic_load(&bar[(8 + g) * 32], __ATOMIC_RELAXED, __HIP_MEMORY_SCOPE_AGENT) < epoch)
        __builtin_amdgcn_s_sleep(1);
    }
  }
  asm volatile("" ::: "memory");
  __syncthreads();
}

// ---------------- fused GEMM + LSTM cell phase ----------------
// 16 waves = 4 K-groups x 4 gate-waves. A: sc-loads -> LDS (bulk, 1 barrier).
// B: direct L2-cached global loads into MFMA frags (no LDS, no inner barriers).
template<int NKT1, int NKTTOT>
__device__ __forceinline__ void lstm_phase(
    const unsigned short* __restrict__ A1, int sA1,
    const unsigned short* __restrict__ A2, int sA2,
    const unsigned short* __restrict__ W, int sW,
    const float* __restrict__ bias,
    float& creg, unsigned short* __restrict__ Hout,
    char* smem, int m0, int n0, int ntile, int tid)
{
  constexpr int BASE = NKTTOT / 4;
  constexpr int REM = NKTTOT % 4;
  constexpr int MAXKT = BASE + (REM ? 1 : 0);

  const int wave = tid >> 6, lane = tid & 63;
  const int grp = wave >> 2, gw = wave & 3;
  const int lrow = lane >> 3, lj = lane & 7;
  const int fl = lane & 15, fh = lane >> 4;

  const int kt0 = grp * BASE + min(grp, REM);
  const int ktn = BASE + (grp < REM ? 1 : 0);

  // ---- bulk A staging: sc-loads to regs, then ds_write, one barrier ----
  char* Ar = smem + grp * 32768;
  const int row = gw * 8 + lrow;
  int4 areg[MAXKT];
#pragma unroll
  for (int i = 0; i < MAXKT; ++i) {
    if (i < ktn) {
      int kt = kt0 + i;
      const unsigned short* src; int col;
      if (kt < NKT1) { src = A1 + (size_t)(m0 + row) * sA1; col = kt * 64; }
      else           { src = A2 + (size_t)(m0 + row) * sA2; col = (kt - NKT1) * 64; }
      areg[i] = ld_coh16(src + col + ((lj ^ (row & 7)) << 3));
    }
  }
  drain_vm();   // inline-asm loads are untracked: wait before consuming areg[]
#pragma unroll
  for (int i = 0; i < MAXKT; ++i)
    if (i < ktn) *(int4*)(Ar + i * 4096 + row * 128 + lj * 16) = areg[i];
  __syncthreads();

  // ---- barrier-free inner loop: B direct from L2, A from LDS ----
  f32x4 acc0 = {0.f, 0.f, 0.f, 0.f}, acc1 = {0.f, 0.f, 0.f, 0.f};
  const unsigned short* Wrow = W + (size_t)(n0 + gw * 16 + fl) * sW + kt0 * 64 + fh * 8;
  const int swz = (fl & 7) << 4;
#pragma unroll
  for (int i = 0; i < MAXKT; ++i) {
    if (i < ktn) {
#pragma unroll
      for (int kk = 0; kk < 2; ++kk) {
        short8 b0 = *(const short8*)(Wrow + i * 64 + kk * 32);
        int colb = kk * 64 + fh * 16;
        short8 a0 = *(const short8*)(Ar + i * 4096 + fl * 128 + (colb ^ swz));
        short8 a1 = *(const short8*)(Ar + i * 4096 + (16 + fl) * 128 + (colb ^ swz));
        acc0 = __builtin_amdgcn_mfma_f32_16x16x32_bf16(a0, b0, acc0, 0, 0, 0);
        acc1 = __builtin_amdgcn_mfma_f32_16x16x32_bf16(a1, b0, acc1, 0, 0, 0);
      }
    }
  }

  // ---- K-partial exchange (reuses LDS) + cell update (C in registers) ----
  __syncthreads();
  float* ex = (float*)smem;
#pragma unroll
  for (int r = 0; r < 4; ++r) {
    ex[((grp * 4 + gw) * 32 + fh * 4 + r) * 16 + fl] = acc0[r];
    ex[((grp * 4 + gw) * 32 + 16 + fh * 4 + r) * 16 + fl] = acc1[r];
  }
  __syncthreads();
  if (tid < 512) {
    int urow = tid >> 4, uu = tid & 15;
    float g4[4];
#pragma unroll
    for (int gg = 0; gg < 4; ++gg) {
      float s = ex[(gg * 32 + urow) * 16 + uu] + ex[((4 + gg) * 32 + urow) * 16 + uu]
              + ex[((8 + gg) * 32 + urow) * 16 + uu] + ex[((12 + gg) * 32 + urow) * 16 + uu];
      g4[gg] = s + bias[n0 + gg * 16 + uu];
    }
    float cn = sigmoidf_(g4[1]) * creg + sigmoidf_(g4[0]) * tanhf(g4[2]);
    creg = cn;
    st_coh2(Hout + (size_t)(m0 + urow) * HH + ntile * 16 + uu,
            (unsigned int)f2bf(sigmoidf_(g4[3]) * tanhf(cn)));
  }
}

// ---------------- decoder phase: 44 active WGs, 16-way K-split ----------------
__device__ __forceinline__ void dec_phase(
    const unsigned short* __restrict__ H3in, const unsigned short* __restrict__ Wd,
    const float* __restrict__ bd, float* __restrict__ out,
    const float* __restrict__ seq, unsigned short* __restrict__ X,
    int gt, int cond, int t, char* smem, int wg, int tid)
{
  if (wg >= 44) return;
  const int wave = tid >> 6, lane = tid & 63;
  const int lrow = lane >> 3, lj = lane & 7;
  const int fl = lane & 15, fh = lane >> 4;
  const int ntile = wg % 11, mtile = wg / 11;
  const int m0 = mtile * 32, n0 = ntile * 16;

  char* Dr = smem + wave * 4096;
  int4 r4[4];
#pragma unroll
  for (int j = 0; j < 4; ++j) {
    int row = j * 8 + lrow;
    r4[j] = ld_coh16(H3in + (size_t)(m0 + row) * HH + wave * 64 + ((lj ^ (row & 7)) << 3));
  }
  drain_vm();   // wait for untracked inline-asm loads before consuming r4[]
#pragma unroll
  for (int j = 0; j < 4; ++j) {
    int row = j * 8 + lrow;
    *(int4*)(Dr + row * 128 + lj * 16) = r4[j];
  }
  __syncthreads();

  f32x4 acc0 = {0.f, 0.f, 0.f, 0.f}, acc1 = {0.f, 0.f, 0.f, 0.f};
  const unsigned short* Wrow = Wd + (size_t)(n0 + fl) * HH + wave * 64 + fh * 8;
  const int swz = (fl & 7) << 4;
#pragma unroll
  for (int kk = 0; kk < 2; ++kk) {
    short8 b0 = *(const short8*)(Wrow + kk * 32);
    int colb = kk * 64 + fh * 16;
    short8 a0 = *(const short8*)(Dr + fl * 128 + (colb ^ swz));
    short8 a1 = *(const short8*)(Dr + (16 + fl) * 128 + (colb ^ swz));
    acc0 = __builtin_amdgcn_mfma_f32_16x16x32_bf16(a0, b0, acc0, 0, 0, 0);
    acc1 = __builtin_amdgcn_mfma_f32_16x16x32_bf16(a1, b0, acc1, 0, 0, 0);
  }

  float* pex = (float*)(smem + 65536);
#pragma unroll
  for (int r = 0; r < 4; ++r) {
    pex[(wave * 32 + fh * 4 + r) * 16 + fl] = acc0[r];
    pex[(wave * 32 + 16 + fh * 4 + r) * 16 + fl] = acc1[r];
  }
  __syncthreads();
  if (tid < 512) {
    int row = tid >> 4, uu = tid & 15;
    int c = n0 + uu;
    if (c < CC) {
      float s = 0.f;
#pragma unroll
      for (int v = 0; v < 16; ++v) s += pex[(v * 32 + row) * 16 + uu];
      float val = s + bd[c];
      int batch = m0 + row;
      out[(size_t)batch * (TT * CC) + (size_t)t * CC + c] = val;
      if (t + 1 < TT) {
        int per = gt + cond;
        bool ug = (per > 0) ? (((t + 1) % per) < gt) : false;
        float xv = ug ? seq[(size_t)batch * (TT * CC) + (size_t)(t + 1) * CC + c] : val;
        st_coh2(X + batch * XPAD + c, (unsigned int)f2bf(xv));
      }
    }
  }
}

// ---------------- persistent megakernel ----------------
__global__ __launch_bounds__(1024, 4) void persistent_lstm(
    const unsigned short* __restrict__ W1, const unsigned short* __restrict__ W2,
    const unsigned short* __restrict__ W3, const unsigned short* __restrict__ Wd,
    const float* __restrict__ B1, const float* __restrict__ B2,
    const float* __restrict__ B3, const float* __restrict__ Bd,
    unsigned short* __restrict__ Hb, unsigned short* __restrict__ X,
    const float* __restrict__ seq, float* __restrict__ out,
    const int* __restrict__ gtp, const int* __restrict__ condp, int* __restrict__ bar)
{
  __shared__ char smem[131072];
  const int wg = blockIdx.x, tid = threadIdx.x;
  // XCD-aware tile map: the 4 WGs sharing a B-panel land on the same XCD (wg%8 = XCD)
  const int xg = wg & 7, sl = wg >> 3;
  const int ntile = xg * 8 + (sl >> 2);
  const int m0 = (sl & 3) * 32;
  const int n0 = ntile * 64;
  const int gt = *gtp, cond = *condp;

  unsigned short* H1[2] = { Hb + 0 * BB * HH, Hb + 1 * BB * HH };
  unsigned short* H2[2] = { Hb + 2 * BB * HH, Hb + 3 * BB * HH };
  unsigned short* H3[2] = { Hb + 4 * BB * HH, Hb + 5 * BB * HH };

  float c1 = 0.f, c2 = 0.f, c3 = 0.f;   // cell state lives in registers (tid<512)

  int epoch = 0;
  for (int t = 0; t < TT; ++t) {
    int p = t & 1;
    lstm_phase<3, 19>(X, XPAD, H1[p], HH, W1, 1216, B1, c1, H1[1 - p], smem, m0, n0, ntile, tid);
    gridbar(bar, wg, tid, ++epoch);
    lstm_phase<16, 32>(H1[1 - p], HH, H2[p], HH, W2, 2048, B2, c2, H2[1 - p], smem, m0, n0, ntile, tid);
    gridbar(bar, wg, tid, ++epoch);
    lstm_phase<16, 32>(H2[1 - p], HH, H3[p], HH, W3, 2048, B3, c3, H3[1 - p], smem, m0, n0, ntile, tid);
    gridbar(bar, wg, tid, ++epoch);
    dec_phase(H3[1 - p], Wd, Bd, out, seq, X, gt, cond, t, smem, wg, tid);
    gridbar(bar, wg, tid, ++epoch);
  }
}

// ---------------- conversion / init kernels ----------------
__device__ __forceinline__ int perm_orig_row(int np) {
  return ((np >> 4) & 3) * HH + ((np >> 6) << 4) + (np & 15);
}

__global__ void conv_w1(const float* __restrict__ Wih, const float* __restrict__ Whh,
                        unsigned short* __restrict__ dst) {
  int k = blockIdx.x * 256 + threadIdx.x;
  int np = blockIdx.y;
  if (k >= 1216) return;
  int n = perm_orig_row(np);
  float v;
  if (k < XPAD) v = (k < CC) ? Wih[(size_t)n * CC + k] : 0.f;
  else          v = Whh[(size_t)n * HH + (k - XPAD)];
  dst[(size_t)np * 1216 + k] = f2bf(v);
}

__global__ void conv_w23(const float* __restrict__ Wih, const float* __restrict__ Whh,
                         unsigned short* __restrict__ dst) {
  int k = blockIdx.x * 256 + threadIdx.x;
  int np = blockIdx.y;
  int n = perm_orig_row(np);
  float v = (k < HH) ? Wih[(size_t)n * HH + k] : Whh[(size_t)n * HH + (k - HH)];
  dst[(size_t)np * 2048 + k] = f2bf(v);
}

__global__ void conv_wd(const float* __restrict__ Wsrc, unsigned short* __restrict__ dst) {
  int k = blockIdx.x * 256 + threadIdx.x;
  int row = blockIdx.y;
  float v = (row < CC) ? Wsrc[(size_t)row * HH + k] : 0.f;
  dst[(size_t)row * HH + k] = f2bf(v);
}

__global__ void conv_bias(const float* bi1, const float* bh1, const float* bi2, const float* bh2,
                          const float* bi3, const float* bh3, const float* bdec,
                          float* o1, float* o2, float* o3, float* od) {
  int idx = blockIdx.x * 256 + threadIdx.x;
  if (idx < 3 * FOURH) {
    int l = idx >> 12; int np = idx & 4095;
    int n = perm_orig_row(np);
    const float* bi = (l == 0) ? bi1 : ((l == 1) ? bi2 : bi3);
    const float* bh = (l == 0) ? bh1 : ((l == 1) ? bh2 : bh3);
    float* o = (l == 0) ? o1 : ((l == 1) ? o2 : o3);
    o[np] = bi[n] + bh[n];
  } else {
    int c2 = idx - 3 * FOURH;
    if (c2 < 176) od[c2] = (c2 < CC) ? bdec[c2] : 0.f;
  }
}

__global__ void init_state(unsigned short* __restrict__ Hall,
                           unsigned short* __restrict__ X, const float* __restrict__ seq,
                           const int* __restrict__ gtp, int* __restrict__ bar) {
  int idx = blockIdx.x * blockDim.x + threadIdx.x;
  if (idx < 3 * 2 * BB * HH) Hall[idx] = 0;
  if (idx < BB * XPAD) {
    int b = idx / XPAD, cc = idx % XPAD;
    float v = 0.f;
    if (cc < CC && (*gtp) > 0) v = seq[(size_t)b * TT * CC + cc];
    X[idx] = f2bf(v);
  }
  if (idx < 1024) bar[idx] = 0;
}

extern "C" void kernel_launch(void* const* d_in, const int* in_sizes, int n_in,
                              void* d_out, int out_size, void* d_ws, size_t ws_size,
                              hipStream_t stream)
{
  const float* seq   = (const float*)d_in[0];
  const float* W_ih1 = (const float*)d_in[1];
  const float* W_hh1 = (const float*)d_in[2];
  const float* b_ih1 = (const float*)d_in[3];
  const float* b_hh1 = (const float*)d_in[4];
  const float* W_ih2 = (const float*)d_in[5];
  const float* W_hh2 = (const float*)d_in[6];
  const float* b_ih2 = (const float*)d_in[7];
  const float* b_hh2 = (const float*)d_in[8];
  const float* W_ih3 = (const float*)d_in[9];
  const float* W_hh3 = (const float*)d_in[10];
  const float* b_ih3 = (const float*)d_in[11];
  const float* b_hh3 = (const float*)d_in[12];
  const float* W_dec = (const float*)d_in[13];
  const float* b_dec = (const float*)d_in[14];
  const int* condp   = (const int*)d_in[15];
  const int* gtp     = (const int*)d_in[16];
  float* out = (float*)d_out;
  char* ws = (char*)d_ws;

  if (ws_size < 47272960) return;

  unsigned short* W1 = (unsigned short*)(ws + 0);
  unsigned short* W2 = (unsigned short*)(ws + 9961472);
  unsigned short* W3 = (unsigned short*)(ws + 26738688);
  unsigned short* Wd = (unsigned short*)(ws + 43515904);
  float* B1 = (float*)(ws + 43876352);
  float* B2 = (float*)(ws + 43941888);
  float* B3 = (float*)(ws + 44007424);
  float* Bd = (float*)(ws + 44072960);
  unsigned short* Hbase = (unsigned short*)(ws + 44073984);
  unsigned short* X = (unsigned short*)(ws + 47219712);
  int* bar = (int*)(ws + 47268864);

  conv_w1 <<<dim3(5, 4096), 256, 0, stream>>>(W_ih1, W_hh1, W1);
  conv_w23<<<dim3(8, 4096), 256, 0, stream>>>(W_ih2, W_hh2, W2);
  conv_w23<<<dim3(8, 4096), 256, 0, stream>>>(W_ih3, W_hh3, W3);
  conv_wd <<<dim3(4, 176),  256, 0, stream>>>(W_dec, Wd);
  conv_bias<<<dim3(49), 256, 0, stream>>>(b_ih1, b_hh1, b_ih2, b_hh2, b_ih3, b_hh3, b_dec,
                                          B1, B2, B3, Bd);
  init_state<<<dim3(3072), 256, 0, stream>>>(Hbase, X, seq, gtp, bar);

  persistent_lstm<<<dim3(256), dim3(1024), 0, stream>>>(
      W1, W2, W3, Wd, B1, B2, B3, Bd, Hbase, X, seq, out, gtp, condp, bar);
}